// Round 1
// baseline (1446.492 us; speedup 1.0000x reference)
//
#include <hip/hip_runtime.h>
#include <math.h>

// RNN: T=4096 sequential steps, B=2048, N_HID=32, N_IN=1.
// Decomposition: thread-per-(batch,h). 64-thread blocks = 1 wave = 2 batch
// elements (lanes 0-31 -> batch b0, lanes 32-63 -> batch b1; h = lane&31).
// h state lives in a tiny per-wave LDS buffer (wave-synchronous, no barrier).
// W_hh row h is register-resident (16 f32x2 -> v_pk_fma_f32 dot).
// Decode (32-dot + sigmoid) fused per step via shfl_xor butterfly.

typedef float f32x2 __attribute__((ext_vector_type(2)));
typedef float f32x4 __attribute__((ext_vector_type(4)));

constexpr int T_STEPS = 4096;
constexpr int BATCH   = 2048;
constexpr int NH      = 32;

__global__ __launch_bounds__(64) void rnn_fused_kernel(
    const float* __restrict__ x,      // [T, B] (N_IN=1)
    const float* __restrict__ hidden, // [B, NH]
    const float* __restrict__ W_ih,   // [NH] (N_IN=1)
    const float* __restrict__ W_hh,   // [NH, NH] row-major: W_hh[h][k]
    const float* __restrict__ b_ih,   // [NH]
    const float* __restrict__ b_hh,   // [NH]
    const float* __restrict__ W_dec,  // [NH] (N_IN=1)
    const float* __restrict__ b_dec,  // [1]
    float* __restrict__ out)          // [T*B] decoded ++ [B*NH] h_final
{
    __shared__ __align__(16) float hbuf[2][NH];

    const int lane = threadIdx.x;     // 0..63
    const int h    = lane & 31;
    const int p    = lane >> 5;       // which of the 2 batch elems
    const int b    = blockIdx.x * 2 + p;

    // Per-lane constants
    const float wih  = W_ih[h];
    const float cb   = b_ih[h] + b_hh[h];
    const float wdec = W_dec[h];
    const float bdec = b_dec[0];

    // W_hh row h -> 16 packed f32x2 registers
    f32x2 wr[16];
    {
        const f32x4* wrow = (const f32x4*)(W_hh + h * NH);
        #pragma unroll
        for (int j = 0; j < 8; ++j) {
            f32x4 v = wrow[j];
            f32x2 lo; lo.x = v.x; lo.y = v.y;
            f32x2 hi; hi.x = v.z; hi.y = v.w;
            wr[2*j]   = lo;
            wr[2*j+1] = hi;
        }
    }

    // Initial hidden state into LDS (wave-synchronous; DS pipe is in-order)
    hbuf[p][h] = hidden[b * NH + h];

    // x prefetch ring (8 deep)
    const float* xb = x + b;
    float xr[8];
    #pragma unroll
    for (int j = 0; j < 8; ++j) xr[j] = xb[(size_t)j * BATCH];

    float* outd = out + b;  // decoded output column for this batch elem
    const f32x4* hp = (const f32x4*)&hbuf[p][0];

    constexpr float LOG2E = 1.44269504088896340736f;
    float hnew = 0.0f;

    for (int t0 = 0; t0 < T_STEPS; t0 += 8) {
        #pragma unroll
        for (int j = 0; j < 8; ++j) {
            const int t = t0 + j;

            // ---- read h_{t-1} (8x ds_read_b128, broadcast within half-wave)
            f32x4 hv[8];
            #pragma unroll
            for (int i = 0; i < 8; ++i) hv[i] = hp[i];

            // ---- 32-MAC dot via 16 packed FMAs, 4 accumulator chains
            f32x2 a0 = {0.f, 0.f}, a1 = {0.f, 0.f}, a2 = {0.f, 0.f}, a3 = {0.f, 0.f};
            #pragma unroll
            for (int i = 0; i < 4; ++i) {
                f32x4 hA = hv[2*i];
                f32x4 hB = hv[2*i+1];
                f32x2 hA0; hA0.x = hA.x; hA0.y = hA.y;
                f32x2 hA1; hA1.x = hA.z; hA1.y = hA.w;
                f32x2 hB0; hB0.x = hB.x; hB0.y = hB.y;
                f32x2 hB1; hB1.x = hB.z; hB1.y = hB.w;
                a0 = __builtin_elementwise_fma(wr[4*i+0], hA0, a0);
                a1 = __builtin_elementwise_fma(wr[4*i+1], hA1, a1);
                a2 = __builtin_elementwise_fma(wr[4*i+2], hB0, a2);
                a3 = __builtin_elementwise_fma(wr[4*i+3], hB1, a3);
            }
            f32x2 s01 = a0 + a1;
            f32x2 s23 = a2 + a3;
            f32x2 sv  = s01 + s23;
            float dotv = sv.x + sv.y;

            // ---- x-projection + relu
            float xp = fmaf(xr[j], wih, cb);
            hnew = fmaxf(dotv + xp, 0.0f);

            // ---- publish h_t for next step
            hbuf[p][h] = hnew;

            // ---- fused decode: sum_h hnew*wdec across 32 lanes, sigmoid
            float d = hnew * wdec;
            d += __shfl_xor(d, 16, 32);
            d += __shfl_xor(d, 8, 32);
            d += __shfl_xor(d, 4, 32);
            d += __shfl_xor(d, 2, 32);
            d += __shfl_xor(d, 1, 32);
            float z = d + bdec;
            // sigmoid(z) = 1/(1+exp(-z)); exp via v_exp_f32 (2^x)
            float e = __builtin_amdgcn_exp2f(-z * LOG2E);
            float sg = __builtin_amdgcn_rcpf(1.0f + e);
            if (h == 0) outd[(size_t)t * BATCH] = sg;

            // ---- prefetch x[t+8] (clamped address, value unused on tail)
            int tp = t + 8;
            tp = (tp < T_STEPS) ? tp : (T_STEPS - 1);
            xr[j] = xb[(size_t)tp * BATCH];
        }
    }

    // ---- final hidden state [B, NH]
    out[(size_t)T_STEPS * BATCH + b * NH + h] = hnew;
}

extern "C" void kernel_launch(void* const* d_in, const int* in_sizes, int n_in,
                              void* d_out, int out_size, void* d_ws, size_t ws_size,
                              hipStream_t stream) {
    const float* x      = (const float*)d_in[0];
    const float* hidden = (const float*)d_in[1];
    const float* W_ih   = (const float*)d_in[2];
    const float* W_hh   = (const float*)d_in[3];
    const float* b_ih   = (const float*)d_in[4];
    const float* b_hh   = (const float*)d_in[5];
    const float* W_dec  = (const float*)d_in[6];
    const float* b_dec  = (const float*)d_in[7];
    float* out          = (float*)d_out;

    dim3 grid(BATCH / 2);   // 1024 blocks, 1 wave each (2 batch elems/wave)
    dim3 block(64);
    hipLaunchKernelGGL(rnn_fused_kernel, grid, block, 0, stream,
                       x, hidden, W_ih, W_hh, b_ih, b_hh, W_dec, b_dec, out);
}